// Round 5
// baseline (254.015 us; speedup 1.0000x reference)
//
#include <hip/hip_runtime.h>
#include <math.h>

#define DIM 512
#define INTER 64
#define N_ROUTED 64
#define TOPK 6
#define NTOK 1024            // B*T
#define CAP 1024             // per-expert token list capacity (worst case)
#define TTILE 16             // tokens per block tile
#define GR 6                 // token-groups (blocks) per routed expert
#define GS 64                // token-groups per shared expert (8 per XCD x 8)

// ---------------------------------------------------------------------------
// Prep: transpose g_w [64][512] -> g_wT [512][64] AND zero the output buffer
// (replaces a separate hipMemsetAsync dispatch).
// ---------------------------------------------------------------------------
__global__ __launch_bounds__(256) void prep_kernel(
    const float* __restrict__ g_w, float* __restrict__ g_wT,
    float* __restrict__ out) {
  __shared__ float tile[32][33];
  const int bd = blockIdx.x;          // 0..15 (d tiles)
  const int be = blockIdx.y;          // 0..1  (e tiles)
  const int c = threadIdx.x & 31;
  const int r = threadIdx.x >> 5;     // 0..7
  #pragma unroll
  for (int k = 0; k < 4; ++k)
    tile[r + k * 8][c] = g_w[(be * 32 + r + k * 8) * DIM + bd * 32 + c];
  __syncthreads();
  #pragma unroll
  for (int k = 0; k < 4; ++k)
    g_wT[(bd * 32 + r + k * 8) * N_ROUTED + be * 32 + c] = tile[c][r + k * 8];

  // zero 1/32 of out (NTOK*DIM floats) per block: 16384 floats = 4096 float4
  const int blk = bd + be * 16;       // 0..31
  float4* ob = (float4*)out + (size_t)blk * 4096;
  #pragma unroll
  for (int k = 0; k < 16; ++k)
    ob[threadIdx.x + k * 256] = make_float4(0.f, 0.f, 0.f, 0.f);
}

// ---------------------------------------------------------------------------
// Gate: one block (256 thr) per token. Waves split depth 4-way; LDS reduce;
// wave 0 does softmax over 64 experts + iterative top-6 argmax on
// (prob + bias) with first-index tie-break (matches lax.top_k).
// 1024 blocks -> 4 blocks/CU -> 16 waves/CU for latency hiding.
// ---------------------------------------------------------------------------
__global__ __launch_bounds__(256) void gate_kernel(
    const float* __restrict__ x, const float* __restrict__ g_wT,
    const float* __restrict__ gate_bias,
    int* __restrict__ choice_idx, float* __restrict__ choice_w) {
  __shared__ float part[4][N_ROUTED];
  const int lane = threadIdx.x & 63;
  const int w = threadIdx.x >> 6;
  const int t = blockIdx.x;
  const float* xr = x + (size_t)t * DIM;

  float acc = 0.f;
  const int d0 = w * 128;
  for (int d = d0; d < d0 + 128; d += 4) {
    const float4 xv = *(const float4*)(xr + d);      // wave-broadcast load
    const float g0 = g_wT[(d + 0) * N_ROUTED + lane];
    const float g1 = g_wT[(d + 1) * N_ROUTED + lane];
    const float g2 = g_wT[(d + 2) * N_ROUTED + lane];
    const float g3 = g_wT[(d + 3) * N_ROUTED + lane];
    acc += xv.x * g0 + xv.y * g1 + xv.z * g2 + xv.w * g3;
  }
  part[w][lane] = acc;
  __syncthreads();

  if (w == 0) {
    acc = part[0][lane] + part[1][lane] + part[2][lane] + part[3][lane];
    float m = acc;
    for (int off = 32; off; off >>= 1) m = fmaxf(m, __shfl_xor(m, off, 64));
    const float p = expf(acc - m);
    float s = p;
    for (int off = 32; off; off >>= 1) s += __shfl_xor(s, off, 64);
    const float prob = p / s;
    float biased = prob + gate_bias[lane];

    for (int k = 0; k < TOPK; ++k) {
      float v = biased;
      int idx = lane;
      for (int off = 1; off < 64; off <<= 1) {
        const float ov = __shfl_xor(v, off, 64);
        const int oi = __shfl_xor(idx, off, 64);
        if (ov > v || (ov == v && oi < idx)) { v = ov; idx = oi; }
      }
      if (lane == idx) {
        choice_idx[t * TOPK + k] = lane;
        choice_w[t * TOPK + k] = prob;    // ROUTE_SCALE == 1.0
        biased = -INFINITY;
      }
    }
  }
}

// ---------------------------------------------------------------------------
// Build per-expert token lists: one block per expert, coalesced scan of the
// dense 6144-entry choice array, LDS position counter.
// ---------------------------------------------------------------------------
__global__ __launch_bounds__(256) void build_lists(
    const int* __restrict__ choice_idx, const float* __restrict__ choice_w,
    int* __restrict__ cnt, int* __restrict__ tlist, float* __restrict__ wlist) {
  __shared__ int lcnt;
  const int e = blockIdx.x;
  if (threadIdx.x == 0) lcnt = 0;
  __syncthreads();
  for (int j = threadIdx.x; j < NTOK * TOPK; j += 256) {
    if (choice_idx[j] == e) {
      const int pos = atomicAdd(&lcnt, 1);
      tlist[e * CAP + pos] = j / TOPK;
      wlist[e * CAP + pos] = choice_w[j];
    }
  }
  __syncthreads();
  if (threadIdx.x == 0) cnt[e] = lcnt;
}

// ---------------------------------------------------------------------------
// Expert FFN: 512-thread blocks (8 waves), 16-token tile.
// XCD-affinity: blockIdx&7 selects XCD (round-robin dispatch heuristic);
// routed expert e only runs on XCD e%8 -> per-XCD L2 weight footprint ~3.8MB.
// Phase A: wave w owns d-slice [w*64,w*64+64) for ALL 16 tokens (lane=inter
//          unit); cross-wave reduce via LDS fp32 atomics into h1s/h3s.
// Phase B: thread owns output col tid (512 cols); coalesced atomicAdd.
// ---------------------------------------------------------------------------
__global__ __launch_bounds__(512, 4) void ffn_kernel(
    const float* __restrict__ x,
    const float* __restrict__ w1, const float* __restrict__ w2,
    const float* __restrict__ w3,
    const int* __restrict__ cnt, const int* __restrict__ tlist,
    const float* __restrict__ wlist,
    float* __restrict__ out) {
  __shared__ float xs[TTILE][DIM];      // 32 KB
  __shared__ float h1s[TTILE][INTER];   // 4 KB
  __shared__ float h3s[TTILE][INTER];   // 4 KB
  __shared__ float as_[TTILE][INTER];   // 4 KB
  __shared__ int   tok[TTILE];
  __shared__ float tw[TTILE];

  const int tid = threadIdx.x;
  const int lane = tid & 63;
  const int w = tid >> 6;               // 0..7

  const int c = blockIdx.x & 7;         // XCD residue
  const int s = blockIdx.x >> 3;        // 0..63 slot within XCD

  int e, g, G, n;
  const int* mylist = nullptr;
  const float* mywl = nullptr;
  if (s < 48) {                         // routed: 8 experts x GR=6 per XCD
    const int ei = s / GR;              // 0..7
    g = s - ei * GR;                    // 0..5
    const int r = ei * 8 + c;           // routed expert id, r%8 == c
    e = r + 2; G = GR; n = cnt[r];
    mylist = tlist + r * CAP;
    mywl = wlist + r * CAP;
  } else {                              // shared: 2 experts x 8 groups per XCD
    const int j = s - 48;               // 0..15
    e = j >> 3;                         // 0..1
    g = c * 8 + (j & 7);                // 0..63
    G = GS; n = NTOK;
  }
  const int m = (n > g) ? (n - g + G - 1) / G : 0;

  const float* w1p = w1 + (size_t)e * DIM * INTER + lane;
  const float* w3p = w3 + (size_t)e * DIM * INTER + lane;
  const float* w2e = w2 + (size_t)e * INTER * DIM;
  const int d0 = w * 64;

  for (int base = 0; base < m; base += TTILE) {
    const int mt = min(TTILE, m - base);
    __syncthreads();                    // prev tile's phase B done with LDS
    if (tid < TTILE) {
      if (tid < mt) {
        const int j = g + (base + tid) * G;
        if (!mylist) { tok[tid] = j; tw[tid] = 1.0f; }
        else         { tok[tid] = mylist[j]; tw[tid] = mywl[j]; }
      } else { tok[tid] = 0; tw[tid] = 0.0f; }
    }
    __syncthreads();

    // stage 16 token rows (coalesced float4) + zero h buffers
    #pragma unroll
    for (int k = 0; k < 4; ++k) {
      const int fidx = tid + k * 512;   // 0..2047 float4 slots
      const int row = fidx >> 7;
      const int c4 = fidx & 127;
      *(float4*)&xs[row][c4 * 4] =
          *(const float4*)(x + (size_t)tok[row] * DIM + c4 * 4);
    }
    #pragma unroll
    for (int k = 0; k < 2; ++k) {
      const int idx = tid + k * 512;    // 0..1023
      ((float*)h1s)[idx] = 0.f;
      ((float*)h3s)[idx] = 0.f;
    }
    __syncthreads();

    // ---- phase A: wave w covers d in [d0, d0+64) for all 16 tokens ----
    float p1[TTILE], p3[TTILE];
    #pragma unroll
    for (int t = 0; t < TTILE; ++t) { p1[t] = 0.f; p3[t] = 0.f; }
    for (int d = d0; d < d0 + 64; d += 4) {
      const float a0 = w1p[(d + 0) << 6];
      const float a1 = w1p[(d + 1) << 6];
      const float a2 = w1p[(d + 2) << 6];
      const float a3 = w1p[(d + 3) << 6];
      const float b0 = w3p[(d + 0) << 6];
      const float b1 = w3p[(d + 1) << 6];
      const float b2 = w3p[(d + 2) << 6];
      const float b3 = w3p[(d + 3) << 6];
      #pragma unroll
      for (int t = 0; t < TTILE; ++t) {
        const float4 xv = *(const float4*)&xs[t][d];   // LDS broadcast
        p1[t] += xv.x * a0 + xv.y * a1 + xv.z * a2 + xv.w * a3;
        p3[t] += xv.x * b0 + xv.y * b1 + xv.z * b2 + xv.w * b3;
      }
    }
    #pragma unroll
    for (int t = 0; t < TTILE; ++t) {
      atomicAdd(&h1s[t][lane], p1[t]);
      atomicAdd(&h3s[t][lane], p3[t]);
    }
    __syncthreads();

    // ---- silu * h3 * route_weight -> as_ ----
    #pragma unroll
    for (int k = 0; k < 2; ++k) {
      const int idx = tid + k * 512;
      const int t = idx >> 6, ii = idx & 63;
      const float h1 = h1s[t][ii];
      as_[t][ii] = (h1 / (1.0f + expf(-h1))) * h3s[t][ii] * tw[t];
    }
    __syncthreads();

    // ---- phase B: thread owns output col tid for all 16 tokens ----
    float o[TTILE];
    #pragma unroll
    for (int t = 0; t < TTILE; ++t) o[t] = 0.f;
    for (int ii = 0; ii < INTER; ii += 4) {
      const float u0 = w2e[(ii + 0) * DIM + tid];
      const float u1 = w2e[(ii + 1) * DIM + tid];
      const float u2 = w2e[(ii + 2) * DIM + tid];
      const float u3 = w2e[(ii + 3) * DIM + tid];
      #pragma unroll
      for (int t = 0; t < TTILE; ++t) {
        const float4 av = *(const float4*)&as_[t][ii];
        o[t] += av.x * u0 + av.y * u1 + av.z * u2 + av.w * u3;
      }
    }
    for (int t = 0; t < mt; ++t)
      atomicAdd(&out[(size_t)tok[t] * DIM + tid], o[t]);
  }
}

extern "C" void kernel_launch(void* const* d_in, const int* in_sizes, int n_in,
                              void* d_out, int out_size, void* d_ws, size_t ws_size,
                              hipStream_t stream) {
  const float* x         = (const float*)d_in[0];
  const float* g_w       = (const float*)d_in[1];
  const float* gate_bias = (const float*)d_in[2];
  const float* w1        = (const float*)d_in[3];
  const float* w2        = (const float*)d_in[4];
  const float* w3        = (const float*)d_in[5];
  float* out = (float*)d_out;

  char* ws = (char*)d_ws;
  int*   cnt     = (int*)ws;                                  // 64 ints (pad 1KB)
  int*   tlist   = (int*)(ws + 1024);                         // 64*1024 ints
  float* wlist   = (float*)(ws + 1024 + N_ROUTED * CAP * 4);  // 64*1024 floats
  float* g_wT    = (float*)(ws + 1024 + N_ROUTED * CAP * 8);  // 512*64 floats
  int*   chidx   = (int*)(ws + 1024 + N_ROUTED * CAP * 8 + DIM * N_ROUTED * 4);
  float* chw     = (float*)((char*)chidx + NTOK * TOPK * 4);

  dim3 tg(DIM / 32, N_ROUTED / 32);
  prep_kernel<<<tg, 256, 0, stream>>>(g_w, g_wT, out);
  gate_kernel<<<NTOK, 256, 0, stream>>>(x, g_wT, gate_bias, chidx, chw);
  build_lists<<<N_ROUTED, 256, 0, stream>>>(chidx, chw, cnt, tlist, wlist);
  ffn_kernel<<<512, 512, 0, stream>>>(x, w1, w2, w3, cnt, tlist, wlist, out);
}

// Round 7
// 183.948 us; speedup vs baseline: 1.3809x; 1.3809x over previous
//
#include <hip/hip_runtime.h>
#include <math.h>

#define DIM 512
#define INTER 64
#define N_ROUTED 64
#define TOPK 6
#define NTOK 1024            // B*T
#define TTILE 16             // tokens per ffn tile
#define GR 8                 // blocks per routed expert (64*8 = 512)
#define GS 64                // blocks per shared expert (2*64 = 128)
#define CHN (NTOK * TOPK)    // 6144 dense choice entries
#define CHUNK (CHN / 256)    // 24 entries per thread in the list scan

// ---------------------------------------------------------------------------
// Gate (dispatch 1 of 2): one block per token.
//  - zeroes this token's output row (replaces memset dispatch)
//  - lane l holds x[l*4..] and x[256+l*4..]; wave w computes experts
//    [w*16,w*16+16) via coalesced g_w ROW loads + butterfly reduce
//    (no transpose kernel, no g_wT workspace)
//  - wave 0: softmax over 64 experts, iterative top-6 argmax on (prob+bias),
//    first-index tie-break (matches lax.top_k), writes dense choice arrays.
// ---------------------------------------------------------------------------
__global__ __launch_bounds__(256) void gate_kernel(
    const float* __restrict__ x, const float* __restrict__ g_w,
    const float* __restrict__ gate_bias,
    int* __restrict__ chidx, float* __restrict__ chw,
    float* __restrict__ out) {
  __shared__ float logits[N_ROUTED];
  const int t = blockIdx.x;
  const int tid = threadIdx.x;
  const int lane = tid & 63;
  const int w = tid >> 6;

  if (tid < 128)
    ((float4*)(out + (size_t)t * DIM))[tid] = make_float4(0.f, 0.f, 0.f, 0.f);

  const float* xr = x + (size_t)t * DIM;
  const float4 xa = *(const float4*)(xr + lane * 4);
  const float4 xb = *(const float4*)(xr + 256 + lane * 4);

  #pragma unroll 4
  for (int k = 0; k < 16; ++k) {
    const int e = w * 16 + k;
    const float* gr = g_w + (size_t)e * DIM;
    const float4 ga = *(const float4*)(gr + lane * 4);
    const float4 gb = *(const float4*)(gr + 256 + lane * 4);
    float v = xa.x * ga.x + xa.y * ga.y + xa.z * ga.z + xa.w * ga.w
            + xb.x * gb.x + xb.y * gb.y + xb.z * gb.z + xb.w * gb.w;
    for (int off = 32; off; off >>= 1) v += __shfl_xor(v, off, 64);
    if (lane == 0) logits[e] = v;
  }
  __syncthreads();

  if (w == 0) {
    const float a = logits[lane];
    float m = a;
    for (int off = 32; off; off >>= 1) m = fmaxf(m, __shfl_xor(m, off, 64));
    const float p = expf(a - m);
    float s = p;
    for (int off = 32; off; off >>= 1) s += __shfl_xor(s, off, 64);
    const float prob = p / s;
    float biased = prob + gate_bias[lane];
    for (int k = 0; k < TOPK; ++k) {
      float v = biased;
      int idx = lane;
      for (int off = 1; off < 64; off <<= 1) {
        const float ov = __shfl_xor(v, off, 64);
        const int oi = __shfl_xor(idx, off, 64);
        if (ov > v || (ov == v && oi < idx)) { v = ov; idx = oi; }
      }
      if (lane == idx) {
        chidx[t * TOPK + k] = lane;
        chw[t * TOPK + k] = prob;      // ROUTE_SCALE == 1.0
        biased = -INFINITY;
      }
    }
  }
}

// ---------------------------------------------------------------------------
// Expert FFN (dispatch 2 of 2): block = (expert, group), XCD-pinned
// (expert r runs only on XCD r%8 via blockIdx&7 round-robin heuristic).
// Routed blocks rebuild their own token sub-list from the dense choices:
// block-wide prefix scan over match counts gives deterministic global ranks
// (scan order fixed -> all GR blocks of an expert agree); block g takes
// ranks == g (mod GR). No build_lists dispatch, no atomics.
// Tile: phase A wave w covers d in [w*128,w*128+128) for all 16 tokens
// (lane = inter unit, weights read once per block, x wave-uniform float4);
// cross-wave reduce + silu*h3*route_w -> as_; phase B thread owns output
// cols (tid, tid+256), coalesced atomicAdd into the pre-zeroed out.
// 37.9 KB LDS + launch_bounds(256,4) -> 4 blocks/CU; 2 barriers per tile.
// ---------------------------------------------------------------------------
__global__ __launch_bounds__(256, 4) void ffn_kernel(
    const float* __restrict__ x,
    const float* __restrict__ w1, const float* __restrict__ w2,
    const float* __restrict__ w3,
    const int* __restrict__ chidx, const float* __restrict__ chw,
    float* __restrict__ out) {
  __shared__ float part1[4][TTILE][INTER];   // 16 KB
  __shared__ float part3[4][TTILE][INTER];   // 16 KB
  __shared__ float as_[TTILE][INTER];        // 4 KB
  __shared__ int   lTok[128];
  __shared__ float lW[128];
  __shared__ int   waveTot[4];

  const int tid = threadIdx.x;
  const int lane = tid & 63;
  const int w = tid >> 6;
  const int blk = blockIdx.x;

  int e, m;
  if (blk < N_ROUTED * GR) {
    // ---- routed: deterministic sub-list build ----
    const int c = blk & 7;          // XCD residue
    const int q = blk >> 3;         // 0..63
    const int ei = q >> 3;          // 0..7
    const int g = q & 7;            // group within expert
    const int r = ei * 8 + c;       // routed expert id (r%8 == c)
    e = r + 2;

    if (tid < 128) { lTok[tid] = 0; lW[tid] = 0.f; }

    const int j0 = tid * CHUNK;
    int cntL = 0;
    #pragma unroll
    for (int k = 0; k < CHUNK; ++k)
      cntL += (chidx[j0 + k] == r) ? 1 : 0;

    int incl = cntL;                // wave-inclusive prefix
    for (int off = 1; off < 64; off <<= 1) {
      const int v = __shfl_up(incl, off, 64);
      if (lane >= off) incl += v;
    }
    if (lane == 63) waveTot[w] = incl;
    __syncthreads();

    int waveOff = 0, nTot = 0;
    #pragma unroll
    for (int i = 0; i < 4; ++i) {
      const int v = waveTot[i];
      nTot += v;
      if (i < w) waveOff += v;
    }
    int rank = waveOff + incl - cntL;   // exclusive global rank
    for (int k = 0; k < CHUNK; ++k) {
      const int j = j0 + k;
      if (chidx[j] == r) {
        if ((rank & 7) == g) {
          lTok[rank >> 3] = j / TOPK;
          lW[rank >> 3] = chw[j];
        }
        ++rank;
      }
    }
    m = (nTot > g) ? ((nTot - g + 7) >> 3) : 0;
    __syncthreads();
  } else {
    // ---- shared experts: tokens g, g+64, ..., weight 1 ----
    const int sb = blk - N_ROUTED * GR;   // 0..127
    e = sb >> 6;
    const int g = sb & 63;
    if (tid < 128) {
      lTok[tid] = (tid < 16) ? (g + tid * GS) : 0;
      lW[tid] = (tid < 16) ? 1.0f : 0.f;
    }
    m = 16;
    __syncthreads();
  }

  const float* w1p = w1 + (size_t)e * DIM * INTER + lane;
  const float* w3p = w3 + (size_t)e * DIM * INTER + lane;
  const float* w2e = w2 + (size_t)e * INTER * DIM;
  const int d0 = w * 128;

  for (int base = 0; base < m; base += TTILE) {
    const int mt = min(TTILE, m - base);
    int tk[TTILE];
    #pragma unroll
    for (int t = 0; t < TTILE; ++t) tk[t] = lTok[base + t];

    // ---- phase A: wave w covers d in [d0,d0+128) for all 16 tokens ----
    float p1[TTILE], p3[TTILE];
    #pragma unroll
    for (int t = 0; t < TTILE; ++t) { p1[t] = 0.f; p3[t] = 0.f; }
    for (int d = d0; d < d0 + 128; d += 4) {
      const float a0 = w1p[(d + 0) << 6];
      const float a1 = w1p[(d + 1) << 6];
      const float a2 = w1p[(d + 2) << 6];
      const float a3 = w1p[(d + 3) << 6];
      const float b0 = w3p[(d + 0) << 6];
      const float b1 = w3p[(d + 1) << 6];
      const float b2 = w3p[(d + 2) << 6];
      const float b3 = w3p[(d + 3) << 6];
      #pragma unroll
      for (int t = 0; t < TTILE; ++t) {
        const float4 xv = *(const float4*)(x + ((size_t)tk[t] << 9) + d);
        p1[t] += xv.x * a0 + xv.y * a1 + xv.z * a2 + xv.w * a3;
        p3[t] += xv.x * b0 + xv.y * b1 + xv.z * b2 + xv.w * b3;
      }
    }
    #pragma unroll
    for (int t = 0; t < TTILE; ++t) {
      part1[w][t][lane] = p1[t];
      part3[w][t][lane] = p3[t];
    }
    __syncthreads();

    // ---- reduce quarters + silu * h3 * route_weight -> as_ ----
    #pragma unroll
    for (int k = 0; k < 4; ++k) {
      const int idx = tid + k * 256;
      const int t = idx >> 6, ii = idx & 63;
      const float h1 = part1[0][t][ii] + part1[1][t][ii] +
                       part1[2][t][ii] + part1[3][t][ii];
      const float h3 = part3[0][t][ii] + part3[1][t][ii] +
                       part3[2][t][ii] + part3[3][t][ii];
      as_[t][ii] = (h1 / (1.0f + expf(-h1))) * h3 * lW[base + t];
    }
    __syncthreads();

    // ---- phase B: thread owns output cols tid and tid+256 ----
    // (next tile's post-A barrier protects as_/part: no trailing sync needed)
    float o0[TTILE], o1[TTILE];
    #pragma unroll
    for (int t = 0; t < TTILE; ++t) { o0[t] = 0.f; o1[t] = 0.f; }
    for (int ii = 0; ii < INTER; ii += 4) {
      const float u0 = w2e[(ii + 0) * DIM + tid];
      const float u1 = w2e[(ii + 1) * DIM + tid];
      const float u2 = w2e[(ii + 2) * DIM + tid];
      const float u3 = w2e[(ii + 3) * DIM + tid];
      const float v0 = w2e[(ii + 0) * DIM + tid + 256];
      const float v1 = w2e[(ii + 1) * DIM + tid + 256];
      const float v2 = w2e[(ii + 2) * DIM + tid + 256];
      const float v3 = w2e[(ii + 3) * DIM + tid + 256];
      #pragma unroll
      for (int t = 0; t < TTILE; ++t) {
        const float4 av = *(const float4*)&as_[t][ii];     // LDS broadcast
        o0[t] += av.x * u0 + av.y * u1 + av.z * u2 + av.w * u3;
        o1[t] += av.x * v0 + av.y * v1 + av.z * v2 + av.w * v3;
      }
    }
    for (int t = 0; t < mt; ++t) {
      atomicAdd(&out[(size_t)tk[t] * DIM + tid], o0[t]);
      atomicAdd(&out[(size_t)tk[t] * DIM + tid + 256], o1[t]);
    }
  }
}

extern "C" void kernel_launch(void* const* d_in, const int* in_sizes, int n_in,
                              void* d_out, int out_size, void* d_ws, size_t ws_size,
                              hipStream_t stream) {
  const float* x         = (const float*)d_in[0];
  const float* g_w       = (const float*)d_in[1];
  const float* gate_bias = (const float*)d_in[2];
  const float* w1        = (const float*)d_in[3];
  const float* w2        = (const float*)d_in[4];
  const float* w3        = (const float*)d_in[5];
  float* out = (float*)d_out;

  int*   chidx = (int*)d_ws;                        // 6144 ints
  float* chw   = (float*)((char*)d_ws + CHN * 4);   // 6144 floats

  gate_kernel<<<NTOK, 256, 0, stream>>>(x, g_w, gate_bias, chidx, chw, out);
  ffn_kernel<<<N_ROUTED * GR + 2 * GS, 256, 0, stream>>>(
      x, w1, w2, w3, chidx, chw, out);
}